// Round 1
// baseline (579.511 us; speedup 1.0000x reference)
//
#include <hip/hip_runtime.h>
#include <hip/hip_bf16.h>
#include <math.h>

// Problem constants
#define B_    64
#define MAXT  511
#define TP1   512
#define S_    1024
#define H_    4096
#define M_TOTAL (B_*TP1)   // 32768 rows

typedef __attribute__((ext_vector_type(8))) short  short8;   // 8 bf16 = 4 VGPRs (MFMA A/B frag)
typedef __attribute__((ext_vector_type(4))) float  float4v;  // MFMA C/D frag

// ---- workspace layout (bytes) ----
// zbuf:  M_TOTAL*4 floats   = 524288
// acc:   1 float (padded)
// Sb:    bf16 s, M_TOTAL*S_ = 67108864
// W1T:   bf16 W1^T, H_*S_   = 8388608
#define ZBUF_BYTES (M_TOTAL*4*sizeof(float))
#define ACC_OFF    ZBUF_BYTES
#define SBF_OFF    0x81000            // 528384, 4K-aligned
#define SBF_BYTES  ((size_t)M_TOTAL*S_*2)
#define W1T_OFF    (SBF_OFF + SBF_BYTES)
#define W1T_BYTES  ((size_t)H_*S_*2)

static __device__ __forceinline__ unsigned short f2bf(float f) {
    unsigned int u = __float_as_uint(f);
    u = u + 0x7fffu + ((u >> 16) & 1u);   // round-to-nearest-even
    return (unsigned short)(u >> 16);
}

static __device__ __forceinline__ void load_lds16(const void* g, void* l) {
    // async 16B/lane global->LDS; LDS dest = wave-uniform base + lane*16
    __builtin_amdgcn_global_load_lds(
        (const __attribute__((address_space(1))) unsigned int*)g,
        (__attribute__((address_space(3))) unsigned int*)l,
        16, 0, 0);
}

// ---- pre-pass: fp32 s -> bf16 (coalesced, 8 elem/thread) ----
__global__ void cvt_s_kernel(const float* __restrict__ s, unsigned short* __restrict__ out) {
    size_t idx = ((size_t)blockIdx.x * 256 + threadIdx.x) * 8;
    float4v f0 = *(const float4v*)(s + idx);
    float4v f1 = *(const float4v*)(s + idx + 4);
    short8 o;
    o[0] = (short)f2bf(f0[0]); o[1] = (short)f2bf(f0[1]);
    o[2] = (short)f2bf(f0[2]); o[3] = (short)f2bf(f0[3]);
    o[4] = (short)f2bf(f1[0]); o[5] = (short)f2bf(f1[1]);
    o[6] = (short)f2bf(f1[2]); o[7] = (short)f2bf(f1[3]);
    *(short8*)(out + idx) = o;
}

// ---- pre-pass: W1 (S x H fp32) -> W1T (H x S bf16), LDS-tiled transpose ----
__global__ void cvt_w1t_kernel(const float* __restrict__ W1, unsigned short* __restrict__ W1T) {
    __shared__ float tile[32][33];
    int h0 = blockIdx.x * 32;   // H dim
    int k0 = blockIdx.y * 32;   // S dim
    int tx = threadIdx.x & 31, ty = threadIdx.x >> 5;  // 32 x 8
    for (int r = ty; r < 32; r += 8)
        tile[r][tx] = W1[(size_t)(k0 + r) * H_ + h0 + tx];
    __syncthreads();
    for (int r = ty; r < 32; r += 8)
        W1T[(size_t)(h0 + r) * S_ + k0 + tx] = f2bf(tile[tx][r]);
}

// ---- main fused GEMM: z[row][0..3] += sum_n relu(s@W1 + b1)[row][n] * W2[n][0..3] ----
// 128x128 tile, BK=32, 4 waves (2x2 of 64x64), mfma_f32_16x16x32_bf16.
// Block skipped entirely when lengths[b] <= tile_t0 (rows never read downstream).
__global__ __launch_bounds__(256) void gemm_fused_kernel(
        const unsigned short* __restrict__ Sb,    // M x S bf16
        const unsigned short* __restrict__ W1T,   // H x S bf16
        const float* __restrict__ b1,             // H
        const float* __restrict__ W2,             // H x 32 fp32 (cols 0..3 used)
        const int*   __restrict__ lengths,        // B
        float*       __restrict__ zbuf)           // M x 4
{
    int ntile = blockIdx.x;          // 0..31  (H/128)
    int mtile = blockIdx.y;          // 0..255 (M/128)
    int b  = mtile >> 2;
    int t0 = (mtile & 3) * 128;
    if (lengths[b] <= t0) return;    // whole tile masked out

    int m0 = mtile * 128;
    int n0 = ntile * 128;

    __shared__ unsigned short smemA[128 * 32];   // 8 KB (rows m, 32 k bf16, 64B/row)
    __shared__ unsigned short smemB[128 * 32];   // 8 KB (rows n of W1T)

    int tid  = threadIdx.x;
    int wid  = tid >> 6;
    int lane = tid & 63;
    int lane15 = lane & 15;
    int quad   = lane >> 4;
    int wave_m = (wid >> 1) * 64;
    int wave_n = (wid & 1) * 64;

    // --- staging constants: chunk c = p*256 + tid; m=c>>2, slot cp=c&3,
    //     global k-chunk q = cp ^ ((m>>1)&3)  (XOR swizzle -> 2-way-free LDS reads)
    int cA0 = tid, cA1 = tid + 256;
    int mA0 = cA0 >> 2, cp0 = cA0 & 3, q0 = cp0 ^ ((mA0 >> 1) & 3);
    int mA1 = cA1 >> 2, cp1 = cA1 & 3, q1 = cp1 ^ ((mA1 >> 1) & 3);

    const char* gA0 = (const char*)Sb  + (size_t)(m0 + mA0) * (S_*2) + q0 * 16;
    const char* gA1 = (const char*)Sb  + (size_t)(m0 + mA1) * (S_*2) + q1 * 16;
    const char* gB0 = (const char*)W1T + (size_t)(n0 + mA0) * (S_*2) + q0 * 16;
    const char* gB1 = (const char*)W1T + (size_t)(n0 + mA1) * (S_*2) + q1 * 16;
    char* lA0 = (char*)smemA + (size_t)(wid * 64) * 16;
    char* lA1 = (char*)smemA + (size_t)(256 + wid * 64) * 16;
    char* lB0 = (char*)smemB + (size_t)(wid * 64) * 16;
    char* lB1 = (char*)smemB + (size_t)(256 + wid * 64) * 16;

    // --- fragment read addresses (constant across K loop) ---
    const unsigned short* aAddr[4];
    const unsigned short* bAddr[4];
#pragma unroll
    for (int s = 0; s < 4; s++) {
        int ml = wave_m + s * 16 + lane15;
        int ca = quad ^ ((ml >> 1) & 3);
        aAddr[s] = smemA + ml * 32 + ca * 8;
        int nl = wave_n + s * 16 + lane15;
        int cb = quad ^ ((nl >> 1) & 3);
        bAddr[s] = smemB + nl * 32 + cb * 8;
    }

    float4v acc[4][4] = {};

    for (int k0i = 0; k0i < S_; k0i += 32) {
        load_lds16(gA0, lA0);
        load_lds16(gA1, lA1);
        load_lds16(gB0, lB0);
        load_lds16(gB1, lB1);
        gA0 += 64; gA1 += 64; gB0 += 64; gB1 += 64;
        __syncthreads();   // staging complete (vmcnt drained by barrier)

        short8 af[4], bf[4];
#pragma unroll
        for (int s = 0; s < 4; s++) {
            af[s] = *(const short8*)aAddr[s];
            bf[s] = *(const short8*)bAddr[s];
        }
#pragma unroll
        for (int i = 0; i < 4; i++)
#pragma unroll
            for (int j = 0; j < 4; j++)
                acc[i][j] = __builtin_amdgcn_mfma_f32_16x16x32_bf16(af[i], bf[j], acc[i][j], 0, 0, 0);
        __syncthreads();   // compute done before next overwrite
    }

    // --- fused epilogue: relu(h) @ W2[:,0:4], shuffle-reduce over the wave's 64 n, atomicAdd ---
    float4v w2r[4];
    float   b1v[4];
#pragma unroll
    for (int ns = 0; ns < 4; ns++) {
        int n_g = n0 + wave_n + ns * 16 + lane15;
        w2r[ns] = *(const float4v*)(W2 + (size_t)n_g * 32);
        b1v[ns] = b1[n_g];
    }
#pragma unroll
    for (int ms = 0; ms < 4; ms++) {
        float p[4][4];
#pragma unroll
        for (int r = 0; r < 4; r++)
#pragma unroll
            for (int c = 0; c < 4; c++) p[r][c] = 0.f;
#pragma unroll
        for (int ns = 0; ns < 4; ns++) {
            float4v av = acc[ms][ns];
#pragma unroll
            for (int r = 0; r < 4; r++) {
                float h = av[r] + b1v[ns];
                h = h > 0.f ? h : 0.f;
                p[r][0] += h * w2r[ns][0];
                p[r][1] += h * w2r[ns][1];
                p[r][2] += h * w2r[ns][2];
                p[r][3] += h * w2r[ns][3];
            }
        }
        // reduce across the 16 lanes holding different n (xor masks 1,2,4,8 stay in-group)
#pragma unroll
        for (int off = 1; off < 16; off <<= 1)
#pragma unroll
            for (int r = 0; r < 4; r++)
#pragma unroll
                for (int c = 0; c < 4; c++)
                    p[r][c] += __shfl_xor(p[r][c], off);
        if (lane15 < 4) {
            int c = lane15;
#pragma unroll
            for (int r = 0; r < 4; r++) {
                int mg = m0 + wave_m + ms * 16 + quad * 4 + r;
                atomicAdd(&zbuf[(size_t)mg * 4 + c], p[r][c]);
            }
        }
    }
}

// ---- log-softmax gather + masked sum ----
__global__ void reduce_logp_kernel(const float* __restrict__ zbuf,
                                   const int*   __restrict__ actions,
                                   const int*   __restrict__ lengths,
                                   const float* __restrict__ b2,
                                   float*       __restrict__ acc)
{
    int b = blockIdx.x;
    int len = lengths[b];
    float b20 = b2[0], b21 = b2[1], b22 = b2[2], b23 = b2[3];
    float local = 0.f;
    for (int t = threadIdx.x; t < MAXT; t += 256) {
        if (t < len) {
            int row = b * TP1 + t;
            float4v z = *(const float4v*)(zbuf + (size_t)row * 4);
            float z0 = z[0] + b20, z1 = z[1] + b21, z2 = z[2] + b22, z3 = z[3] + b23;
            float mx = fmaxf(fmaxf(z0, z1), fmaxf(z2, z3));
            float se = expf(z0 - mx) + expf(z1 - mx) + expf(z2 - mx) + expf(z3 - mx);
            int a = actions[b * MAXT + t];
            float za = (a == 0) ? z0 : (a == 1) ? z1 : (a == 2) ? z2 : z3;
            local += (za - mx) - logf(se);
        }
    }
#pragma unroll
    for (int off = 32; off > 0; off >>= 1) local += __shfl_xor(local, off);
    __shared__ float wsum[4];
    if ((threadIdx.x & 63) == 0) wsum[threadIdx.x >> 6] = local;
    __syncthreads();
    if (threadIdx.x == 0)
        atomicAdd(acc, wsum[0] + wsum[1] + wsum[2] + wsum[3]);
}

__global__ void finalize_kernel(const float* __restrict__ acc, float* __restrict__ out) {
    out[0] = -acc[0];
}

extern "C" void kernel_launch(void* const* d_in, const int* in_sizes, int n_in,
                              void* d_out, int out_size, void* d_ws, size_t ws_size,
                              hipStream_t stream) {
    const float* s       = (const float*)d_in[0];  // (64,512,1024) fp32
    const int*   actions = (const int*)  d_in[1];  // (64,511)
    const int*   lengths = (const int*)  d_in[2];  // (64,)
    const float* W1      = (const float*)d_in[3];  // (1024,4096)
    const float* b1      = (const float*)d_in[4];  // (4096,)
    const float* W2      = (const float*)d_in[5];  // (4096,32)
    const float* b2      = (const float*)d_in[6];  // (32,)

    char* ws = (char*)d_ws;
    float*          zbuf = (float*)ws;
    float*          acc  = (float*)(ws + ACC_OFF);
    unsigned short* Sb   = (unsigned short*)(ws + SBF_OFF);
    unsigned short* W1T  = (unsigned short*)(ws + W1T_OFF);

    // zero z-buffer + accumulator (ws is poisoned 0xAA before every launch)
    hipMemsetAsync(ws, 0, ZBUF_BYTES + 256, stream);

    // s -> bf16 : 33.5M elems, 8/thread
    cvt_s_kernel<<<dim3((M_TOTAL * S_) / (256 * 8)), 256, 0, stream>>>(s, Sb);
    // W1 -> bf16 transposed (H x S)
    cvt_w1t_kernel<<<dim3(H_ / 32, S_ / 32), 256, 0, stream>>>(W1, W1T);
    // fused GEMM + relu + W2[:,0:4] projection
    gemm_fused_kernel<<<dim3(H_ / 128, M_TOTAL / 128), 256, 0, stream>>>(
        Sb, W1T, b1, W2, lengths, zbuf);
    // log-softmax gather + masked sum
    reduce_logp_kernel<<<dim3(B_), 256, 0, stream>>>(zbuf, actions, lengths, b2, acc);
    finalize_kernel<<<dim3(1), 1, 0, stream>>>(acc, (float*)d_out);
}